// Round 1
// baseline (215.719 us; speedup 1.0000x reference)
//
#include <hip/hip_runtime.h>
#include <hip/hip_bf16.h>

#define DIMC 64
#define NPOS 2744      // 14^3
#define BB 4
#define BNTOT (BB*NPOS)   // 10976
#define RELVOL 19683   // 27^3
#define MPAD 2816      // 22*128
#define MC 128
#define NCHUNK 22

typedef __bf16 bf16x8 __attribute__((ext_vector_type(8)));
typedef float f32x16 __attribute__((ext_vector_type(16)));

// ---- workspace layout (bytes) ----
#define WS_Q  0u           // f32 [4][64][2744]
#define WS_K  2809856u     // f32 [4][16][2744]
#define WS_V  3512320u     // f32 [4][16][2744]
#define WS_ST 4214784u     // f32 [160]: [0..63] scale_q, [64..127] shift_q, [128..143] scale_v, [144..159] shift_v
#define WS_LC 4215552u     // f32 [4][16][16] lambda_c
#define WS_EB 4219648u     // u16 [16][19683] bf16 E table, k-major
#define WS_VB 4849664u     // u16 [4][16][2816] bf16 v_bn, zero-padded

__device__ inline unsigned short f2bf(float f) {
  unsigned int u = __float_as_uint(f);
  return (unsigned short)((u + 0x7fffu + ((u >> 16) & 1u)) >> 16);
}

// ---------------- K1: qkv projections ----------------
// grid = 43 n-blocks * 4 o-quarters; each thread: one (b,n), 24 output channels
__global__ __launch_bounds__(256) void k_qkv(const float* __restrict__ x,
    const float* __restrict__ Wq, const float* __restrict__ Wk, const float* __restrict__ Wv,
    float* __restrict__ qws, float* __restrict__ kws, float* __restrict__ vws) {
  int oq = blockIdx.x & 3, nb = blockIdx.x >> 2;
  int tid = threadIdx.x;
  int gid = nb * 256 + tid;
  if (gid >= BNTOT) return;
  int b = gid / NPOS, n = gid - b * NPOS;
  const float* xp = x + (size_t)b * 64 * NPOS + n;

  const float* wp[24];
  float acc[24];
#pragma unroll
  for (int j = 0; j < 24; ++j) {
    int ch = oq * 24 + j;
    wp[j] = (ch < 64) ? (Wq + ch * 64) : ((ch < 80) ? (Wk + (ch - 64) * 64) : (Wv + (ch - 80) * 64));
    acc[j] = 0.f;
  }
  for (int c = 0; c < 64; c += 4) {
    float x0 = xp[(c + 0) * NPOS], x1 = xp[(c + 1) * NPOS];
    float x2 = xp[(c + 2) * NPOS], x3 = xp[(c + 3) * NPOS];
#pragma unroll
    for (int j = 0; j < 24; ++j) {
      float4 w = *(const float4*)(wp[j] + c);
      acc[j] += w.x * x0 + w.y * x1 + w.z * x2 + w.w * x3;
    }
  }
#pragma unroll
  for (int j = 0; j < 24; ++j) {
    int ch = oq * 24 + j;
    if (ch < 64)      qws[((size_t)b * 64 + ch) * NPOS + n] = acc[j];
    else if (ch < 80) kws[((size_t)b * 16 + (ch - 64)) * NPOS + n] = acc[j];
    else              vws[((size_t)b * 16 + (ch - 80)) * NPOS + n] = acc[j];
  }
}

// ---------------- K2: batchnorm stats -> scale/shift ----------------
// grid = 80 blocks (64 q channels + 16 v channels)
__global__ __launch_bounds__(256) void k_stats(const float* __restrict__ qws, const float* __restrict__ vws,
    const float* __restrict__ gq, const float* __restrict__ bq,
    const float* __restrict__ gv, const float* __restrict__ bv, float* __restrict__ st) {
  int ch = blockIdx.x;
  int tid = threadIdx.x;
  float s = 0.f, ss = 0.f;
  for (int b = 0; b < 4; ++b) {
    const float* p = (ch < 64) ? (qws + ((size_t)b * 64 + ch) * NPOS)
                               : (vws + ((size_t)b * 16 + (ch - 64)) * NPOS);
    for (int n = tid; n < NPOS; n += 256) { float v = p[n]; s += v; ss += v * v; }
  }
#pragma unroll
  for (int o = 32; o > 0; o >>= 1) { s += __shfl_xor(s, o, 64); ss += __shfl_xor(ss, o, 64); }
  __shared__ float rs[4], rss[4];
  int wid = tid >> 6;
  if ((tid & 63) == 0) { rs[wid] = s; rss[wid] = ss; }
  __syncthreads();
  if (tid == 0) {
    float S = rs[0] + rs[1] + rs[2] + rs[3];
    float SS = rss[0] + rss[1] + rss[2] + rss[3];
    float mean = S / (float)BNTOT;
    float var = SS / (float)BNTOT - mean * mean;
    float inv = rsqrtf(var + 1e-5f);
    float g, be;
    if (ch < 64) { g = gq[ch]; be = bq[ch]; } else { g = gv[ch - 64]; be = bv[ch - 64]; }
    float sc = g * inv, sh = be - mean * sc;
    if (ch < 64) { st[ch] = sc; st[64 + ch] = sh; }
    else { st[128 + (ch - 64)] = sc; st[144 + (ch - 64)] = sh; }
  }
}

// ---------------- K3: bf16 conversions ----------------
// ebt[k][i] = bf16(rpe[i*16+k]); vbt[b][v][m] = bf16(BN(v)), zero pad m>=2744
__global__ __launch_bounds__(256) void k_conv(const float* __restrict__ rpe, const float* __restrict__ vws,
    const float* __restrict__ st, unsigned short* __restrict__ ebt, unsigned short* __restrict__ vbt) {
  int tid = blockIdx.x * 256 + threadIdx.x;
  int stride = gridDim.x * 256;
  const int TOT = 16 * RELVOL + 4 * 16 * MPAD;
  for (int idx = tid; idx < TOT; idx += stride) {
    if (idx < 16 * RELVOL) {
      int k = idx / RELVOL, i = idx - k * RELVOL;
      ebt[idx] = f2bf(rpe[i * 16 + k]);
    } else {
      int t = idx - 16 * RELVOL;
      int b = t / (16 * MPAD); int r = t - b * 16 * MPAD;
      int v = r / MPAD; int m = r - v * MPAD;
      float val = 0.f;
      if (m < NPOS) val = vws[((size_t)b * 16 + v) * NPOS + m] * st[128 + v] + st[144 + v];
      vbt[t] = f2bf(val);
    }
  }
}

// ---------------- K4: softmax(k) + lambda_c ----------------
// grid = 64 blocks (b,kc)
__global__ __launch_bounds__(256) void k_lamc(const float* __restrict__ kws, const float* __restrict__ vws,
    const float* __restrict__ st, float* __restrict__ lc) {
  int b = blockIdx.x >> 4, kc = blockIdx.x & 15;
  int tid = threadIdx.x;
  const float* kp = kws + ((size_t)b * 16 + kc) * NPOS;
  float mx = -1e30f;
  for (int m = tid; m < NPOS; m += 256) mx = fmaxf(mx, kp[m]);
#pragma unroll
  for (int o = 32; o > 0; o >>= 1) mx = fmaxf(mx, __shfl_xor(mx, o, 64));
  __shared__ float rmx[4];
  int wid = tid >> 6;
  if ((tid & 63) == 0) rmx[wid] = mx;
  __syncthreads();
  mx = fmaxf(fmaxf(rmx[0], rmx[1]), fmaxf(rmx[2], rmx[3]));
  float scv[16], shv[16];
#pragma unroll
  for (int v = 0; v < 16; ++v) { scv[v] = st[128 + v]; shv[v] = st[144 + v]; }
  float s = 0.f, acc[16];
#pragma unroll
  for (int v = 0; v < 16; ++v) acc[v] = 0.f;
  for (int m = tid; m < NPOS; m += 256) {
    float e = __expf(kp[m] - mx);
    s += e;
#pragma unroll
    for (int v = 0; v < 16; ++v)
      acc[v] += e * (vws[((size_t)b * 16 + v) * NPOS + m] * scv[v] + shv[v]);
  }
#pragma unroll
  for (int o = 32; o > 0; o >>= 1) {
    s += __shfl_xor(s, o, 64);
#pragma unroll
    for (int v = 0; v < 16; ++v) acc[v] += __shfl_xor(acc[v], o, 64);
  }
  __shared__ float red[17][4];
  if ((tid & 63) == 0) { red[16][wid] = s; for (int v = 0; v < 16; ++v) red[v][wid] = acc[v]; }
  __syncthreads();
  if (tid == 0) {
    float S = red[16][0] + red[16][1] + red[16][2] + red[16][3];
    float invS = 1.f / S;
    for (int v = 0; v < 16; ++v) {
      float A = red[v][0] + red[v][1] + red[v][2] + red[v][3];
      lc[((size_t)b * 16 + kc) * 16 + v] = A * invS;
    }
  }
}

// ---------------- K5: main MFMA kernel ----------------
// 686 blocks * 256 thr; block handles 4 query positions n0..n0+3.
// wave w: npair=w>>1 (rows: 2 n's x 16 k), bpair=w&1 (cols: 2 b's x 16 v), one 32x32 acc tile.
// LDS: 4 E regions [16k][128m] bf16 (swizzled), 4 V regions [16v][128m] bf16 (swizzled), pmc table.
__global__ __launch_bounds__(256) void k_main(const unsigned short* __restrict__ ebt,
    const unsigned short* __restrict__ vbt, const float* __restrict__ qws,
    const float* __restrict__ st, const float* __restrict__ lc, float* __restrict__ out) {
  __shared__ alignas(16) unsigned char smem[38400];
  unsigned short* pmc = (unsigned short*)(smem + 32768);
  int tid = threadIdx.x;
  int w = tid >> 6, l = tid & 63;
  int n0 = blockIdx.x * 4;

  // per-m position code table: zm*729 + ym*27 + xm  (clamped at m=2743 for pad rows)
  for (int i = tid; i < MPAD; i += 256) {
    int m = (i < NPOS) ? i : (NPOS - 1);
    int zm = m / 196; int t = m - zm * 196;
    int ym = t / 14;  int xm = t - ym * 14;
    pmc[i] = (unsigned short)(zm * 729 + ym * 27 + xm);
  }
  // base for this wave's staging n:  eidx = pmc[m] + base_n
  int nst = n0 + w;
  int zn = nst / 196; int tt = nst - zn * 196;
  int yn = tt / 14;   int xn = tt - yn * 14;
  int base_n = 9841 - (zn * 729 + yn * 27 + xn);   // 13*(729+27+1) - pos_n code
  __syncthreads();

  int npair = w >> 1, bpair = w & 1;
  int sig = l >> 5, sel = (l >> 4) & 1, rowk = l & 15;
  int regA = (npair * 2 + sel) * 4096;            // E region for this lane's row half
  int regB = 16384 + (bpair * 2 + sel) * 4096;    // V region for this lane's col half
  int rowoff = rowk * 256;
  int mask = (rowk & 7) << 4;
  int sig16 = sig * 16;

  f32x16 acc;
#pragma unroll
  for (int i = 0; i < 16; ++i) acc[i] = 0.f;

  for (int ci = 0; ci < NCHUNK; ++ci) {
    int m0 = ci * MC;
    // ---- stage E region w: logical element e = k*128 + mcol, written swizzled ----
#pragma unroll
    for (int i = 0; i < 32; ++i) {
      int e = i * 64 + l;
      int k = e >> 7;
      int mcol = e & 127;
      int eidx = (int)pmc[m0 + mcol] + base_n;
      unsigned short val = ebt[k * RELVOL + eidx];
      int phys = (2 * mcol) ^ ((k & 7) << 4);
      *(unsigned short*)(smem + w * 4096 + k * 256 + phys) = val;
    }
    // ---- stage V region w (b = w): contiguous 16B per lane, written swizzled ----
#pragma unroll
    for (int i = 0; i < 4; ++i) {
      int e8 = i * 512 + l * 8;
      int vrow = e8 >> 7;
      int mcol = e8 & 127;
      uint4 val = *(const uint4*)(vbt + ((size_t)w * 16 + vrow) * MPAD + m0 + mcol);
      int phys = (2 * mcol) ^ ((vrow & 7) << 4);
      *(uint4*)(smem + 16384 + w * 4096 + vrow * 256 + phys) = val;
    }
    __syncthreads();
    // ---- 8 K-steps of 32x32x16 MFMA ----
#pragma unroll
    for (int ks = 0; ks < 8; ++ks) {
      int off = rowoff + ((ks * 32 + sig16) ^ mask);
      uint4 ua = *(const uint4*)(smem + regA + off);
      uint4 ub = *(const uint4*)(smem + regB + off);
      acc = __builtin_amdgcn_mfma_f32_32x32x16_bf16(__builtin_bit_cast(bf16x8, ua),
            __builtin_bit_cast(bf16x8, ub), acc, 0, 0, 0);
    }
    __syncthreads();
  }

  // ---- epilogue: Y[b,h,v,n] = sum_k q_bn[b,h*16+k,n] * (lambda_p + lambda_c)[b,k,v] ----
  // C/D: col = l&31 -> (b_sel, v); reg r -> row = (r&3) + 8*(r>>2) + 4*sig -> (n_sel = r>>3, kk)
  int v = rowk;
  int b = bpair * 2 + sel;
  float lam[16];
#pragma unroll
  for (int r = 0; r < 16; ++r) {
    int kk = (r & 3) + 4 * sig + 8 * ((r >> 2) & 1);
    lam[r] = acc[r] + lc[((size_t)b * 16 + kk) * 16 + v];
  }
#pragma unroll
  for (int ns = 0; ns < 2; ++ns) {
    int n = n0 + npair * 2 + ns;
#pragma unroll
    for (int h = 0; h < 4; ++h) {
      float part = 0.f;
#pragma unroll
      for (int rr = 0; rr < 8; ++rr) {
        int r = ns * 8 + rr;
        int kk = (rr & 3) + 4 * sig + 8 * ((rr >> 2) & 1);
        int ch = h * 16 + kk;
        float qv = qws[((size_t)b * 64 + ch) * NPOS + n] * st[ch] + st[64 + ch];
        part += qv * lam[r];
      }
      part += __shfl_xor(part, 32, 64);
      if (sig == 0) out[((size_t)b * 64 + h * 16 + v) * NPOS + n] = part;
    }
  }
}

extern "C" void kernel_launch(void* const* d_in, const int* in_sizes, int n_in,
                              void* d_out, int out_size, void* d_ws, size_t ws_size,
                              hipStream_t stream) {
  const float* x   = (const float*)d_in[0];
  const float* Wq  = (const float*)d_in[1];
  const float* Wk  = (const float*)d_in[2];
  const float* Wv  = (const float*)d_in[3];
  const float* rpe = (const float*)d_in[4];
  const float* gq  = (const float*)d_in[5];
  const float* bq  = (const float*)d_in[6];
  const float* gv  = (const float*)d_in[7];
  const float* bv  = (const float*)d_in[8];
  float* out = (float*)d_out;
  char* ws = (char*)d_ws;
  float* qws = (float*)(ws + WS_Q);
  float* kws = (float*)(ws + WS_K);
  float* vws = (float*)(ws + WS_V);
  float* st  = (float*)(ws + WS_ST);
  float* lcp = (float*)(ws + WS_LC);
  unsigned short* ebt = (unsigned short*)(ws + WS_EB);
  unsigned short* vbt = (unsigned short*)(ws + WS_VB);

  k_qkv<<<172, 256, 0, stream>>>(x, Wq, Wk, Wv, qws, kws, vws);
  k_stats<<<80, 256, 0, stream>>>(qws, vws, gq, bq, gv, bv, st);
  k_conv<<<512, 256, 0, stream>>>(rpe, vws, st, ebt, vbt);
  k_lamc<<<64, 256, 0, stream>>>(kws, vws, st, lcp);
  k_main<<<686, 256, 0, stream>>>(ebt, vbt, qws, st, lcp, out);
}

// Round 2
// 114.625 us; speedup vs baseline: 1.8820x; 1.8820x over previous
//
#include <hip/hip_runtime.h>
#include <hip/hip_bf16.h>

#define NPOS 2744      // 14^3
#define BB 4
#define BNTOT (BB*NPOS)   // 10976
#define RELVOL 19683   // 27^3
#define CPAD 178       // vfrag c-slots: 176 real (2816 m) + 2 pad
#define NPAIR 1372

typedef __bf16 bf16x8 __attribute__((ext_vector_type(8)));
typedef float f32x16 __attribute__((ext_vector_type(16)));

// ---- workspace layout (bytes) ----
#define WS_Q  0u           // f32 [4][64][2744]
#define WS_K  2809856u     // f32 [4][16][2744]  (dead after k_lamc; reused below)
#define WS_V  3512320u     // f32 [4][16][2744]
#define WS_ST 4214784u     // f32 [160]
#define WS_LC 4215552u     // f32 [4][16][16]
#define WS_E2 4219648u     // u16 [19683][16]  bf16 E table, k-MINOR (flat == rpe layout)
#define WS_VF WS_K                     // uint4 [2][178][64]  v B-fragments (alias of dead kws)
#define WS_PM (WS_K + 364544u)         // u16 [2880] position codes (padded)

__device__ inline unsigned short f2bf(float f) {
  unsigned int u = __float_as_uint(f);
  return (unsigned short)((u + 0x7fffu + ((u >> 16) & 1u)) >> 16);
}

// ---------------- K1: qkv projections ----------------
__global__ __launch_bounds__(256) void k_qkv(const float* __restrict__ x,
    const float* __restrict__ Wq, const float* __restrict__ Wk, const float* __restrict__ Wv,
    float* __restrict__ qws, float* __restrict__ kws, float* __restrict__ vws) {
  int oq = blockIdx.x & 3, nb = blockIdx.x >> 2;
  int tid = threadIdx.x;
  int gid = nb * 256 + tid;
  if (gid >= BNTOT) return;
  int b = gid / NPOS, n = gid - b * NPOS;
  const float* xp = x + (size_t)b * 64 * NPOS + n;

  const float* wp[24];
  float acc[24];
#pragma unroll
  for (int j = 0; j < 24; ++j) {
    int ch = oq * 24 + j;
    wp[j] = (ch < 64) ? (Wq + ch * 64) : ((ch < 80) ? (Wk + (ch - 64) * 64) : (Wv + (ch - 80) * 64));
    acc[j] = 0.f;
  }
  for (int c = 0; c < 64; c += 4) {
    float x0 = xp[(c + 0) * NPOS], x1 = xp[(c + 1) * NPOS];
    float x2 = xp[(c + 2) * NPOS], x3 = xp[(c + 3) * NPOS];
#pragma unroll
    for (int j = 0; j < 24; ++j) {
      float4 w = *(const float4*)(wp[j] + c);
      acc[j] += w.x * x0 + w.y * x1 + w.z * x2 + w.w * x3;
    }
  }
#pragma unroll
  for (int j = 0; j < 24; ++j) {
    int ch = oq * 24 + j;
    if (ch < 64)      qws[((size_t)b * 64 + ch) * NPOS + n] = acc[j];
    else if (ch < 80) kws[((size_t)b * 16 + (ch - 64)) * NPOS + n] = acc[j];
    else              vws[((size_t)b * 16 + (ch - 80)) * NPOS + n] = acc[j];
  }
}

// ---------------- K2: batchnorm stats -> scale/shift ----------------
__global__ __launch_bounds__(256) void k_stats(const float* __restrict__ qws, const float* __restrict__ vws,
    const float* __restrict__ gq, const float* __restrict__ bq,
    const float* __restrict__ gv, const float* __restrict__ bv, float* __restrict__ st) {
  int ch = blockIdx.x;
  int tid = threadIdx.x;
  float s = 0.f, ss = 0.f;
  for (int b = 0; b < 4; ++b) {
    const float* p = (ch < 64) ? (qws + ((size_t)b * 64 + ch) * NPOS)
                               : (vws + ((size_t)b * 16 + (ch - 64)) * NPOS);
    for (int n = tid; n < NPOS; n += 256) { float v = p[n]; s += v; ss += v * v; }
  }
#pragma unroll
  for (int o = 32; o > 0; o >>= 1) { s += __shfl_xor(s, o, 64); ss += __shfl_xor(ss, o, 64); }
  __shared__ float rs[4], rss[4];
  int wid = tid >> 6;
  if ((tid & 63) == 0) { rs[wid] = s; rss[wid] = ss; }
  __syncthreads();
  if (tid == 0) {
    float S = rs[0] + rs[1] + rs[2] + rs[3];
    float SS = rss[0] + rss[1] + rss[2] + rss[3];
    float mean = S / (float)BNTOT;
    float var = SS / (float)BNTOT - mean * mean;
    float inv = rsqrtf(var + 1e-5f);
    float g, be;
    if (ch < 64) { g = gq[ch]; be = bq[ch]; } else { g = gv[ch - 64]; be = bv[ch - 64]; }
    float sc = g * inv, sh = be - mean * sc;
    if (ch < 64) { st[ch] = sc; st[64 + ch] = sh; }
    else { st[128 + (ch - 64)] = sc; st[144 + (ch - 64)] = sh; }
  }
}

// ---------------- K3: softmax(k) + lambda_c ----------------
__global__ __launch_bounds__(256) void k_lamc(const float* __restrict__ kws, const float* __restrict__ vws,
    const float* __restrict__ st, float* __restrict__ lc) {
  int b = blockIdx.x >> 4, kc = blockIdx.x & 15;
  int tid = threadIdx.x;
  const float* kp = kws + ((size_t)b * 16 + kc) * NPOS;
  float mx = -1e30f;
  for (int m = tid; m < NPOS; m += 256) mx = fmaxf(mx, kp[m]);
#pragma unroll
  for (int o = 32; o > 0; o >>= 1) mx = fmaxf(mx, __shfl_xor(mx, o, 64));
  __shared__ float rmx[4];
  int wid = tid >> 6;
  if ((tid & 63) == 0) rmx[wid] = mx;
  __syncthreads();
  mx = fmaxf(fmaxf(rmx[0], rmx[1]), fmaxf(rmx[2], rmx[3]));
  float scv[16], shv[16];
#pragma unroll
  for (int v = 0; v < 16; ++v) { scv[v] = st[128 + v]; shv[v] = st[144 + v]; }
  float s = 0.f, acc[16];
#pragma unroll
  for (int v = 0; v < 16; ++v) acc[v] = 0.f;
  for (int m = tid; m < NPOS; m += 256) {
    float e = __expf(kp[m] - mx);
    s += e;
#pragma unroll
    for (int v = 0; v < 16; ++v)
      acc[v] += e * (vws[((size_t)b * 16 + v) * NPOS + m] * scv[v] + shv[v]);
  }
#pragma unroll
  for (int o = 32; o > 0; o >>= 1) {
    s += __shfl_xor(s, o, 64);
#pragma unroll
    for (int v = 0; v < 16; ++v) acc[v] += __shfl_xor(acc[v], o, 64);
  }
  __shared__ float red[17][4];
  if ((tid & 63) == 0) { red[16][wid] = s; for (int v = 0; v < 16; ++v) red[v][wid] = acc[v]; }
  __syncthreads();
  if (tid == 0) {
    float S = red[16][0] + red[16][1] + red[16][2] + red[16][3];
    float invS = 1.f / S;
    for (int v = 0; v < 16; ++v) {
      float A = red[v][0] + red[v][1] + red[v][2] + red[v][3];
      lc[((size_t)b * 16 + kc) * 16 + v] = A * invS;
    }
  }
}

// ---------------- K4: bf16 tables: ebt2 (k-minor E), vfrag (v B-fragments), pmcg ----------------
__global__ __launch_bounds__(256) void k_conv(const float* __restrict__ rpe,
    const float* __restrict__ vws, const float* __restrict__ st,
    unsigned short* __restrict__ ebt2, uint4* __restrict__ vfrag,
    unsigned short* __restrict__ pmcg) {
  int tid = blockIdx.x * 256 + threadIdx.x;
  int stride = gridDim.x * 256;
  const int N1 = 16 * RELVOL;        // 314928 : ebt2 flat == rpe flat
  const int N2 = 2 * CPAD * 64;      // 22784  : vfrag entries
  const int N3 = 2880;               // pmcg (padded)
  const int TOT = N1 + N2 + N3;
  for (int idx = tid; idx < TOT; idx += stride) {
    if (idx < N1) {
      ebt2[idx] = f2bf(rpe[idx]);
    } else if (idx < N1 + N2) {
      int t = idx - N1;
      int ct = t / (CPAD * 64); int r = t - ct * (CPAD * 64);
      int c = r >> 6, l = r & 63;
      int b = ct * 2 + ((l >> 4) & 1), v = l & 15;
      int mu0 = c * 16 + (l >> 5) * 8;
      float sc = st[128 + v], sh = st[144 + v];
      unsigned int wds[4];
#pragma unroll
      for (int i = 0; i < 4; ++i) {
        float f0 = 0.f, f1 = 0.f;
        int m0 = mu0 + 2 * i, m1 = m0 + 1;
        if (m0 < NPOS) f0 = vws[((size_t)b * 16 + v) * NPOS + m0] * sc + sh;
        if (m1 < NPOS) f1 = vws[((size_t)b * 16 + v) * NPOS + m1] * sc + sh;
        wds[i] = (unsigned int)f2bf(f0) | ((unsigned int)f2bf(f1) << 16);
      }
      vfrag[(ct * CPAD + c) * 64 + l] = make_uint4(wds[0], wds[1], wds[2], wds[3]);
    } else {
      int i3 = idx - N1 - N2;
      int m = (i3 < NPOS) ? i3 : (NPOS - 1);
      int zm = m / 196; int t2 = m - zm * 196; int ym = t2 / 14; int xm = t2 - ym * 14;
      pmcg[i3] = (unsigned short)(zm * 729 + ym * 27 + xm);
    }
  }
}

// ---------------- K5: main lambda_p MFMA kernel (LDS-free main loop) ----------------
// block = 128 thr = 2 waves, one n-pair per block. Wave w covers m in [w*1408, w*1408+1408).
// Per 32-m double-step: gather E rows for n0/n1 (16B/lane), transpose via 2 identity-MFMAs,
// pack to bf16, 4 real MFMAs against precomputed v fragments. No LDS, no barriers in loop.
#define PKHI(hi, lo) __builtin_amdgcn_perm(__float_as_uint(hi), __float_as_uint(lo), 0x07060302u)

__global__ __launch_bounds__(128) void k_lam(const unsigned short* __restrict__ ebt2,
    const unsigned short* __restrict__ pmcg, const uint4* __restrict__ vfrag,
    const float* __restrict__ qws, const float* __restrict__ st,
    const float* __restrict__ lc, float* __restrict__ out) {
  __shared__ float red[2048];
  int tid = threadIdx.x;
  int w = tid >> 6, l = tid & 63;
  int np = blockIdx.x;
  int n0 = np * 2, n1 = n0 + 1;
  int zn = n0 / 196; int t0 = n0 - zn * 196; int yn = t0 / 14; int xn = t0 - yn * 14;
  int base0 = 9841 - (zn * 729 + yn * 27 + xn);
  int zn1 = n1 / 196; int t1 = n1 - zn1 * 196; int yn1 = t1 / 14; int xn1 = t1 - yn1 * 14;
  int base1 = 9841 - (zn1 * 729 + yn1 * 27 + xn1);

  int p = l & 31;
  int fl = (p & 19) | ((p & 4) << 1) | ((p & 8) >> 1);   // swap bits 2<->3
  int kh = l >> 5;

  // identity B-fragments for the transpose MFMAs
  uint4 bi = make_uint4(0, 0, 0, 0);
  int j0 = (l & 15) - kh * 8;
  if (j0 >= 0 && j0 < 8) {
    unsigned int one = 0x3F80u << (16 * (j0 & 1));
    if ((j0 >> 1) == 0) bi.x = one; else if ((j0 >> 1) == 1) bi.y = one;
    else if ((j0 >> 1) == 2) bi.z = one; else bi.w = one;
  }
  uint4 zero4 = make_uint4(0, 0, 0, 0);
  uint4 bI0 = (l & 16) ? zero4 : bi;   // fills A-rows 0..15  (n0)
  uint4 bI1 = (l & 16) ? bi : zero4;   // fills A-rows 16..31 (n1)

  f32x16 acc0, acc1, zz;
#pragma unroll
  for (int i = 0; i < 16; ++i) { acc0[i] = 0.f; acc1[i] = 0.f; zz[i] = 0.f; }

  int dS = w * 44, dE = dS + 44;
  const unsigned short* pmp = pmcg + fl;

  unsigned short pmc_ = pmp[dS * 32];
  unsigned short pmn = pmp[(dS + 1) * 32];
  uint4 A0, A1, B0, B1, B2, B3;
  {
    int e0 = (int)pmc_ + base0, e1 = (int)pmc_ + base1;
    A0 = *(const uint4*)(ebt2 + e0 * 16 + kh * 8);
    A1 = *(const uint4*)(ebt2 + e1 * 16 + kh * 8);
    const uint4* vf = vfrag + (size_t)(2 * dS) * 64 + l;
    B0 = vf[0]; B1 = vf[64]; B2 = vf[CPAD * 64]; B3 = vf[CPAD * 64 + 64];
  }
  for (int d = dS; d < dE; ++d) {
    unsigned short pm2 = pmp[(d + 2) * 32];
    uint4 nA0, nA1, nB0, nB1, nB2, nB3;
    {
      int e0 = (int)pmn + base0, e1 = (int)pmn + base1;
      nA0 = *(const uint4*)(ebt2 + e0 * 16 + kh * 8);
      nA1 = *(const uint4*)(ebt2 + e1 * 16 + kh * 8);
      const uint4* vf = vfrag + (size_t)(2 * (d + 1)) * 64 + l;
      nB0 = vf[0]; nB1 = vf[64]; nB2 = vf[CPAD * 64]; nB3 = vf[CPAD * 64 + 64];
    }
    // transpose through the matrix pipe
    f32x16 tr = __builtin_amdgcn_mfma_f32_32x32x16_bf16(
        __builtin_bit_cast(bf16x8, A0), __builtin_bit_cast(bf16x8, bI0), zz, 0, 0, 0);
    tr = __builtin_amdgcn_mfma_f32_32x32x16_bf16(
        __builtin_bit_cast(bf16x8, A1), __builtin_bit_cast(bf16x8, bI1), tr, 0, 0, 0);
    // pack exact-bf16 f32 pairs -> two A fragments (regs 0..7 = first 16 m, 8..15 = next 16)
    uint4 alo, ahi;
    alo.x = PKHI(tr[1], tr[0]);  alo.y = PKHI(tr[3], tr[2]);
    alo.z = PKHI(tr[5], tr[4]);  alo.w = PKHI(tr[7], tr[6]);
    ahi.x = PKHI(tr[9], tr[8]);  ahi.y = PKHI(tr[11], tr[10]);
    ahi.z = PKHI(tr[13], tr[12]); ahi.w = PKHI(tr[15], tr[14]);
    acc0 = __builtin_amdgcn_mfma_f32_32x32x16_bf16(
        __builtin_bit_cast(bf16x8, alo), __builtin_bit_cast(bf16x8, B0), acc0, 0, 0, 0);
    acc0 = __builtin_amdgcn_mfma_f32_32x32x16_bf16(
        __builtin_bit_cast(bf16x8, ahi), __builtin_bit_cast(bf16x8, B1), acc0, 0, 0, 0);
    acc1 = __builtin_amdgcn_mfma_f32_32x32x16_bf16(
        __builtin_bit_cast(bf16x8, alo), __builtin_bit_cast(bf16x8, B2), acc1, 0, 0, 0);
    acc1 = __builtin_amdgcn_mfma_f32_32x32x16_bf16(
        __builtin_bit_cast(bf16x8, ahi), __builtin_bit_cast(bf16x8, B3), acc1, 0, 0, 0);
    A0 = nA0; A1 = nA1; B0 = nB0; B1 = nB1; B2 = nB2; B3 = nB3;
    pmc_ = pmn; pmn = pm2;
  }

  // ---- cross-wave reduction ----
  if (w == 1) {
#pragma unroll
    for (int r = 0; r < 16; ++r) { red[r * 64 + l] = acc0[r]; red[1024 + r * 64 + l] = acc1[r]; }
  }
  __syncthreads();
  if (w == 0) {
#pragma unroll
    for (int r = 0; r < 16; ++r) { acc0[r] += red[r * 64 + l]; acc1[r] += red[1024 + r * 64 + l]; }
    int sig = kh;
    int bsel = (l >> 4) & 1, v = l & 15;
#pragma unroll
    for (int ct = 0; ct < 2; ++ct) {
      int b = ct * 2 + bsel;
      float lam[16];
#pragma unroll
      for (int r = 0; r < 16; ++r) {
        int kk = (r & 3) + 4 * sig + 8 * ((r >> 2) & 1);
        lam[r] = (ct ? acc1[r] : acc0[r]) + lc[((size_t)b * 16 + kk) * 16 + v];
      }
#pragma unroll
      for (int ns = 0; ns < 2; ++ns) {
        int n = np * 2 + ns;
#pragma unroll
        for (int h = 0; h < 4; ++h) {
          float part = 0.f;
#pragma unroll
          for (int rr = 0; rr < 8; ++rr) {
            int kk = (rr & 3) + 4 * sig + 8 * ((rr >> 2) & 1);
            int ch = h * 16 + kk;
            float qv = qws[((size_t)b * 64 + ch) * NPOS + n] * st[ch] + st[64 + ch];
            part += qv * lam[ns * 8 + rr];
          }
          part += __shfl_xor(part, 32, 64);
          if (sig == 0) out[((size_t)b * 64 + h * 16 + v) * NPOS + n] = part;
        }
      }
    }
  }
}

extern "C" void kernel_launch(void* const* d_in, const int* in_sizes, int n_in,
                              void* d_out, int out_size, void* d_ws, size_t ws_size,
                              hipStream_t stream) {
  const float* x   = (const float*)d_in[0];
  const float* Wq  = (const float*)d_in[1];
  const float* Wk  = (const float*)d_in[2];
  const float* Wv  = (const float*)d_in[3];
  const float* rpe = (const float*)d_in[4];
  const float* gq  = (const float*)d_in[5];
  const float* bq  = (const float*)d_in[6];
  const float* gv  = (const float*)d_in[7];
  const float* bv  = (const float*)d_in[8];
  float* out = (float*)d_out;
  char* ws = (char*)d_ws;
  float* qws = (float*)(ws + WS_Q);
  float* kws = (float*)(ws + WS_K);
  float* vws = (float*)(ws + WS_V);
  float* st  = (float*)(ws + WS_ST);
  float* lcp = (float*)(ws + WS_LC);
  unsigned short* ebt2 = (unsigned short*)(ws + WS_E2);
  uint4* vfrag = (uint4*)(ws + WS_VF);
  unsigned short* pmcg = (unsigned short*)(ws + WS_PM);

  k_qkv<<<172, 256, 0, stream>>>(x, Wq, Wk, Wv, qws, kws, vws);
  k_stats<<<80, 256, 0, stream>>>(qws, vws, gq, bq, gv, bv, st);
  k_lamc<<<64, 256, 0, stream>>>(kws, vws, st, lcp);   // kws dead after this
  k_conv<<<512, 256, 0, stream>>>(rpe, vws, st, ebt2, vfrag, pmcg);  // vfrag aliases kws
  k_lam<<<NPAIR, 128, 0, stream>>>(ebt2, pmcg, vfrag, qws, st, lcp, out);
}